// Round 6
// baseline (113.950 us; speedup 1.0000x reference)
//
#include <hip/hip_runtime.h>
#include <hip/hip_bf16.h>

typedef unsigned short u16;
typedef __attribute__((ext_vector_type(8))) short short8;
typedef __attribute__((ext_vector_type(4))) float f32x4;

#define NROWS 4096
#define DIM   512
#define TINV  10.0f   // 1/temperature
#define NTILE 64      // 4096/64 : one 64x64 tile per WAVE
#define NT    2080    // NTILE*(NTILE+1)/2 triangular tiles
#define NBLK  520     // NT/4 waves per block

// round-to-nearest-even f32 -> bf16 bits
__device__ __forceinline__ u16 f2bf(float x) {
    unsigned u = __float_as_uint(x);
    unsigned r = (u + 0x7FFFu + ((u >> 16) & 1u)) >> 16;
    return (u16)r;
}

// ---------------------------------------------------------------------------
// Kernel 1: L2-normalize rows -> bf16; zero the S accumulator.
// ---------------------------------------------------------------------------
__global__ __launch_bounds__(256) void k_norm(const float* __restrict__ in,
                                              u16* __restrict__ out,
                                              float* __restrict__ S) {
    const int row  = blockIdx.x * 4 + (threadIdx.x >> 6);
    const int lane = threadIdx.x & 63;
    if (threadIdx.x < 4) S[blockIdx.x * 4 + threadIdx.x] = 0.f;

    const float* rp = in + (size_t)row * DIM;
    float4 v0 = ((const float4*)rp)[lane];
    float4 v1 = ((const float4*)rp)[lane + 64];

    float ssq = v0.x*v0.x + v0.y*v0.y + v0.z*v0.z + v0.w*v0.w
              + v1.x*v1.x + v1.y*v1.y + v1.z*v1.z + v1.w*v1.w;
    #pragma unroll
    for (int m = 32; m; m >>= 1) ssq += __shfl_xor(ssq, m);

    const float scale = 1.0f / fmaxf(sqrtf(ssq), 1e-12f);

    u16* op = out + (size_t)row * DIM;
    ((ushort4*)op)[lane] = make_ushort4(
        f2bf(v0.x * scale), f2bf(v0.y * scale),
        f2bf(v0.z * scale), f2bf(v0.w * scale));
    ((ushort4*)op)[lane + 64] = make_ushort4(
        f2bf(v1.x * scale), f2bf(v1.y * scale),
        f2bf(v1.z * scale), f2bf(v1.w * scale));
}

// ---------------------------------------------------------------------------
// Kernel 2: LDS-free register GEMM. One WAVE owns one 64x64 tile of the
// upper triangle of sim = f f^T. Fragments are loaded straight from global
// (lane lr,kg reads f[row+lr][kg*8..+8] = 16 contiguous bytes; the 4 MB
// feature array is L2-resident). NO __syncthreads, NO LDS -> every wave
// streams independently; compiler pipelines loads with counted vmcnt.
// Round-4/5 lesson: stage+barrier structure was latency-bound at 5% MfmaUtil.
// ---------------------------------------------------------------------------
__global__ __launch_bounds__(256) void k_gemm(const u16* __restrict__ fb,
                                              float* __restrict__ S,
                                              float* __restrict__ P) {
    // XCD-bijective block swizzle (520 % 8 == 0): consecutive tiles of the
    // same row-panel land on the same XCD's L2.
    const int swz = (blockIdx.x & 7) * (NBLK / 8) + (blockIdx.x >> 3);
    const int t   = swz * 4 + (threadIdx.x >> 6);   // wave's triangular tile id

    // decode t -> (br, bc), off(br) = br*(129-br)/2
    int br = (int)((129.0f - sqrtf(16641.0f - 8.0f * (float)t)) * 0.5f);
    br = br < 0 ? 0 : (br > 63 ? 63 : br);
    while (br * (129 - br) / 2 > t) --br;
    while ((br + 1) * (128 - br) / 2 <= t) ++br;
    const int bc = br + (t - br * (129 - br) / 2);

    const bool diag = (br == bc);
    const bool posT = (bc == (br ^ 32));   // tile holding positive pairs

    const int lane = threadIdx.x & 63;
    const int lr   = lane & 15;
    const int kg   = lane >> 4;
    const int brow = br * 64;
    const int bcol = bc * 64;

    // per-lane fragment base offsets (elements)
    const u16* pa = fb + (size_t)(brow + lr) * DIM + kg * 8;
    const u16* pb = fb + (size_t)(bcol + lr) * DIM + kg * 8;

    f32x4 acc[4][4];
    #pragma unroll
    for (int m = 0; m < 4; ++m)
        #pragma unroll
        for (int n = 0; n < 4; ++n)
            acc[m][n] = (f32x4){0.f, 0.f, 0.f, 0.f};

    if (diag) {
        #pragma unroll 4
        for (int kk = 0; kk < DIM; kk += 32) {
            short8 a[4];
            #pragma unroll
            for (int m = 0; m < 4; ++m)
                a[m] = *(const short8*)(pa + (size_t)(m * 16) * DIM + kk);
            #pragma unroll
            for (int m = 0; m < 4; ++m)
                #pragma unroll
                for (int n = 0; n < 4; ++n)
                    acc[m][n] = __builtin_amdgcn_mfma_f32_16x16x32_bf16(
                        a[m], a[n], acc[m][n], 0, 0, 0);
        }
    } else {
        #pragma unroll 4
        for (int kk = 0; kk < DIM; kk += 32) {
            short8 a[4], b[4];
            #pragma unroll
            for (int m = 0; m < 4; ++m)
                a[m] = *(const short8*)(pa + (size_t)(m * 16) * DIM + kk);
            #pragma unroll
            for (int n = 0; n < 4; ++n)
                b[n] = *(const short8*)(pb + (size_t)(n * 16) * DIM + kk);
            #pragma unroll
            for (int m = 0; m < 4; ++m)
                #pragma unroll
                for (int n = 0; n < 4; ++n)
                    acc[m][n] = __builtin_amdgcn_mfma_f32_16x16x32_bf16(
                        a[m], b[n], acc[m][n], 0, 0, 0);
        }
    }

    // ---- epilogue ----
    // C/D layout: col = lane&15, row = (lane>>4)*4 + reg   [m89]
    float cs[4] = {0.f, 0.f, 0.f, 0.f};
    #pragma unroll
    for (int m = 0; m < 4; ++m) {
        #pragma unroll
        for (int r = 0; r < 4; ++r) {
            const int grow = brow + m * 16 + kg * 4 + r;
            float rs = 0.f;
            #pragma unroll
            for (int n = 0; n < 4; ++n) {
                const int gcol = bcol + n * 16 + lr;
                const float s = acc[m][n][r];
                if (posT && gcol == (grow ^ 2048)) { P[grow] = s; P[gcol] = s; }
                float e = __expf(TINV * (s - 1.0f));
                if (diag && gcol == grow) e = 0.f;
                rs += e;
                if (!diag) cs[n] += e;
            }
            rs += __shfl_xor(rs, 1);
            rs += __shfl_xor(rs, 2);
            rs += __shfl_xor(rs, 4);
            rs += __shfl_xor(rs, 8);
            if (lr == 0) atomicAdd(&S[grow], rs);
        }
    }
    if (!diag) {
        #pragma unroll
        for (int n = 0; n < 4; ++n) {
            cs[n] += __shfl_xor(cs[n], 16);
            cs[n] += __shfl_xor(cs[n], 32);
            if (kg == 0)
                atomicAdd(&S[bcol + n * 16 + lr], cs[n]);
        }
    }
}

// ---------------------------------------------------------------------------
// Kernel 3: loss = mean_i (1/T + log S_i - P_i/T)
// ---------------------------------------------------------------------------
__global__ __launch_bounds__(1024) void k_final(const float* __restrict__ S,
                                                const float* __restrict__ P,
                                                float* __restrict__ out) {
    __shared__ float red[1024];
    float local = 0.f;
    #pragma unroll
    for (int i = 0; i < 4; ++i) {
        const int r = threadIdx.x + i * 1024;
        local += TINV + logf(S[r]) - TINV * P[r];
    }
    red[threadIdx.x] = local;
    __syncthreads();
    #pragma unroll
    for (int s = 512; s; s >>= 1) {
        if (threadIdx.x < s) red[threadIdx.x] += red[threadIdx.x + s];
        __syncthreads();
    }
    if (threadIdx.x == 0) out[0] = red[0] * (1.0f / NROWS);
}

// ---------------------------------------------------------------------------
extern "C" void kernel_launch(void* const* d_in, const int* in_sizes, int n_in,
                              void* d_out, int out_size, void* d_ws, size_t ws_size,
                              hipStream_t stream) {
    const float* feat = (const float*)d_in[0];

    u16*   fb = (u16*)d_ws;                                      // 4 MB
    float* S  = (float*)((char*)d_ws + (size_t)NROWS * DIM * 2); // 16 KB
    float* P  = S + NROWS;                                       // 16 KB

    k_norm<<<NROWS / 4, 256, 0, stream>>>(feat, fb, S);
    k_gemm<<<NBLK, 256, 0, stream>>>(fb, S, P);
    k_final<<<1, 1024, 0, stream>>>(S, P, (float*)d_out);
}

// Round 8
// 94.219 us; speedup vs baseline: 1.2094x; 1.2094x over previous
//
#include <hip/hip_runtime.h>
#include <hip/hip_bf16.h>

typedef unsigned short u16;
typedef __attribute__((ext_vector_type(8))) short short8;
typedef __attribute__((ext_vector_type(4))) float f32x4;

#define NROWS 4096
#define DIM   512
#define TINV  10.0f   // 1/temperature

// round-to-nearest-even f32 -> bf16 bits
__device__ __forceinline__ u16 f2bf(float x) {
    unsigned u = __float_as_uint(x);
    unsigned r = (u + 0x7FFFu + ((u >> 16) & 1u)) >> 16;
    return (u16)r;
}

// ---------------------------------------------------------------------------
// Kernel 1: L2-normalize rows -> bf16; zero the S accumulator.
// ---------------------------------------------------------------------------
__global__ __launch_bounds__(256) void k_norm(const float* __restrict__ in,
                                              u16* __restrict__ out,
                                              float* __restrict__ S) {
    const int row  = blockIdx.x * 4 + (threadIdx.x >> 6);
    const int lane = threadIdx.x & 63;
    if (threadIdx.x < 4) S[blockIdx.x * 4 + threadIdx.x] = 0.f;

    const float* rp = in + (size_t)row * DIM;
    float4 v0 = ((const float4*)rp)[lane];
    float4 v1 = ((const float4*)rp)[lane + 64];

    float ssq = v0.x*v0.x + v0.y*v0.y + v0.z*v0.z + v0.w*v0.w
              + v1.x*v1.x + v1.y*v1.y + v1.z*v1.z + v1.w*v1.w;
    #pragma unroll
    for (int m = 32; m; m >>= 1) ssq += __shfl_xor(ssq, m);

    const float scale = 1.0f / fmaxf(sqrtf(ssq), 1e-12f);

    u16* op = out + (size_t)row * DIM;
    ((ushort4*)op)[lane] = make_ushort4(
        f2bf(v0.x * scale), f2bf(v0.y * scale),
        f2bf(v0.z * scale), f2bf(v0.w * scale));
    ((ushort4*)op)[lane + 64] = make_ushort4(
        f2bf(v1.x * scale), f2bf(v1.y * scale),
        f2bf(v1.z * scale), f2bf(v1.w * scale));
}

// ---------------------------------------------------------------------------
// Kernel 2: persistent-A GEMM, 256 blocks (= 1/CU, perfect balance).
// Block (br = id>>3, bcg = id&7): rows [br*128, +128) x cols [bcg*512, +512).
//   - A panel 128x512 bf16 = 128 KB staged in LDS ONCE (prologue).
//   - B tiles 128x64 = 16 KB double-buffered; stage(s+1) issued before
//     compute(s), one barrier per step (T3-minimum 2-phase).
//   - bcg = id&7 => round-robin XCD mapping gives each XCD one bcg class;
//     B footprint (512 KB) identical within class => L2-hot.
// Full square (no triangular symmetry): 2x MFMA (pipe was 5% busy) for
// perfect balance, row-sums only, trivial positive/diagonal handling.
// Swizzle: LDS chunk c holds global chunk c ^ (row&7); read with same XOR.
// NOTE (round 7): no LDS-pointer ARRAYS — gfx950 rejects the addrspacecast
// static initializer. Use scalar pointers + ternary select.
// ---------------------------------------------------------------------------
__device__ __forceinline__ void gload_lds16(const u16* g, u16* l) {
    __builtin_amdgcn_global_load_lds(
        (const __attribute__((address_space(1))) void*)g,
        (__attribute__((address_space(3))) void*)l, 16, 0, 0);
}

#define LDS_A_ELEMS (128 * 512)          // 128 KB
#define LDS_B_ELEMS (128 * 64)           // 16 KB per buffer
#define LDS_BYTES   ((LDS_A_ELEMS + 2 * LDS_B_ELEMS) * 2)   // 163840

__global__ __launch_bounds__(256) void k_gemm(const u16* __restrict__ fb,
                                              float* __restrict__ S,
                                              float* __restrict__ P) {
    extern __shared__ u16 lds[];
    u16* lA  = lds;                              // [128][64 chunks]
    u16* lB0 = lds + LDS_A_ELEMS;
    u16* lB1 = lds + LDS_A_ELEMS + LDS_B_ELEMS;

    const int br  = blockIdx.x >> 3;
    const int bcg = blockIdx.x & 7;

    const int tid  = threadIdx.x;
    const int lane = tid & 63;
    const int wid  = tid >> 6;
    const int wr   = wid >> 1;                   // 64-row half
    const int wc   = wid & 1;                    // 64-col half (within bc tile)
    const int lr   = lane & 15;
    const int kg   = lane >> 4;

    const u16* Abase = fb + (size_t)(br * 128) * DIM;
    const u16* Bbase = fb + (size_t)(bcg * 512) * DIM;

    // ---- prologue: stage A panel (8192 chunks) + B tile for step 0 ----
    #pragma unroll
    for (int i = 0; i < 32; ++i) {
        const int q  = tid + i * 256;            // chunk id 0..8191
        const int r  = q >> 6;                   // row 0..127
        const int c  = q & 63;                   // dest chunk
        const int sc = c ^ (r & 7);              // swizzled source chunk
        gload_lds16(Abase + (size_t)r * DIM + sc * 8, lA + q * 8);
    }
    #pragma unroll
    for (int i = 0; i < 4; ++i) {                // B step 0: bct=0, kk=0
        const int q  = tid + i * 256;            // chunk id 0..1023
        const int r  = q >> 3;                   // row 0..127
        const int c  = q & 7;
        const int sc = c ^ (r & 7);
        gload_lds16(Bbase + (size_t)r * DIM + sc * 8, lB0 + q * 8);
    }
    __syncthreads();

    float rsum[4][4];
    #pragma unroll
    for (int m = 0; m < 4; ++m)
        #pragma unroll
        for (int r = 0; r < 4; ++r) rsum[m][r] = 0.f;

    #pragma unroll 1
    for (int bct = 0; bct < 4; ++bct) {
        f32x4 acc[4][4];
        #pragma unroll
        for (int m = 0; m < 4; ++m)
            #pragma unroll
            for (int n = 0; n < 4; ++n)
                acc[m][n] = (f32x4){0.f, 0.f, 0.f, 0.f};

        #pragma unroll 1
        for (int k8 = 0; k8 < 8; ++k8) {
            const int s = bct * 8 + k8;
            // ---- stage next B tile into the other buffer ----
            if (s < 31) {
                const int sn   = s + 1;
                const int bctn = sn >> 3;
                const int kkn  = (sn & 7) * 64;
                u16* dst = (sn & 1) ? lB1 : lB0;
                #pragma unroll
                for (int i = 0; i < 4; ++i) {
                    const int q  = tid + i * 256;
                    const int r  = q >> 3;
                    const int c  = q & 7;
                    const int sc = c ^ (r & 7);
                    gload_lds16(Bbase + (size_t)(bctn * 128 + r) * DIM + kkn + sc * 8,
                                dst + q * 8);
                }
            }
            // ---- fragments from LDS (swizzled reads) ----
            const int kk = k8 * 64;
            const u16* bbuf = (s & 1) ? lB1 : lB0;
            short8 a[4][2], b[4][2];
            #pragma unroll
            for (int m = 0; m < 4; ++m) {
                const int row = wr * 64 + m * 16 + lr;
                #pragma unroll
                for (int ks = 0; ks < 2; ++ks) {
                    const int kc = (kk >> 3) + ks * 4 + kg;      // global chunk
                    a[m][ks] = *(const short8*)
                        &lA[(row * 64 + (kc ^ (row & 7))) * 8];
                }
            }
            #pragma unroll
            for (int n = 0; n < 4; ++n) {
                const int row = wc * 64 + n * 16 + lr;
                #pragma unroll
                for (int ks = 0; ks < 2; ++ks) {
                    const int kc = ks * 4 + kg;                  // local chunk
                    b[n][ks] = *(const short8*)
                        &bbuf[(row * 8 + (kc ^ (row & 7))) * 8];
                }
            }
            #pragma unroll
            for (int ks = 0; ks < 2; ++ks)
                #pragma unroll
                for (int m = 0; m < 4; ++m)
                    #pragma unroll
                    for (int n = 0; n < 4; ++n)
                        acc[m][n] = __builtin_amdgcn_mfma_f32_16x16x32_bf16(
                            a[m][ks], b[n][ks], acc[m][n], 0, 0, 0);
            __syncthreads();   // drains stage (vmcnt) + guards buffer reuse
        }

        // ---- per-bc epilogue: exp, diag mask, positive, accumulate ----
        // C/D layout: col = lane&15, row = (lane>>4)*4 + reg   [m89]
        const int bc_abs = bcg * 4 + bct;
        const bool posT  = (bc_abs == (br ^ 16));
        #pragma unroll
        for (int m = 0; m < 4; ++m) {
            #pragma unroll
            for (int r = 0; r < 4; ++r) {
                const int grow = br * 128 + wr * 64 + m * 16 + kg * 4 + r;
                #pragma unroll
                for (int n = 0; n < 4; ++n) {
                    const int gcol = bc_abs * 128 + wc * 64 + n * 16 + lr;
                    const float sv = acc[m][n][r];
                    if (posT && gcol == (grow ^ 2048)) P[grow] = sv;
                    float e = __expf(TINV * (sv - 1.0f));
                    if (gcol == grow) e = 0.f;
                    rsum[m][r] += e;
                }
            }
        }
    }

    // ---- final: reduce rsum over the 16-lane col group, one atomic/row ----
    #pragma unroll
    for (int m = 0; m < 4; ++m) {
        #pragma unroll
        for (int r = 0; r < 4; ++r) {
            float rs = rsum[m][r];
            rs += __shfl_xor(rs, 1);
            rs += __shfl_xor(rs, 2);
            rs += __shfl_xor(rs, 4);
            rs += __shfl_xor(rs, 8);
            if (lr == 0) {
                const int grow = br * 128 + wr * 64 + m * 16 + kg * 4 + r;
                atomicAdd(&S[grow], rs);
            }
        }
    }
}

// ---------------------------------------------------------------------------
// Kernel 3: loss = mean_i (1/T + log S_i - P_i/T)
// ---------------------------------------------------------------------------
__global__ __launch_bounds__(1024) void k_final(const float* __restrict__ S,
                                                const float* __restrict__ P,
                                                float* __restrict__ out) {
    __shared__ float red[1024];
    float local = 0.f;
    #pragma unroll
    for (int i = 0; i < 4; ++i) {
        const int r = threadIdx.x + i * 1024;
        local += TINV + logf(S[r]) - TINV * P[r];
    }
    red[threadIdx.x] = local;
    __syncthreads();
    #pragma unroll
    for (int s = 512; s; s >>= 1) {
        if (threadIdx.x < s) red[threadIdx.x] += red[threadIdx.x + s];
        __syncthreads();
    }
    if (threadIdx.x == 0) out[0] = red[0] * (1.0f / NROWS);
}

// ---------------------------------------------------------------------------
extern "C" void kernel_launch(void* const* d_in, const int* in_sizes, int n_in,
                              void* d_out, int out_size, void* d_ws, size_t ws_size,
                              hipStream_t stream) {
    const float* feat = (const float*)d_in[0];

    u16*   fb = (u16*)d_ws;                                      // 4 MB
    float* S  = (float*)((char*)d_ws + (size_t)NROWS * DIM * 2); // 16 KB
    float* P  = S + NROWS;                                       // 16 KB

    // allow 160 KB dynamic LDS (host-side attribute, graph-capture safe)
    (void)hipFuncSetAttribute((const void*)k_gemm,
                              hipFuncAttributeMaxDynamicSharedMemorySize,
                              LDS_BYTES);

    k_norm<<<NROWS / 4, 256, 0, stream>>>(feat, fb, S);
    k_gemm<<<256, 256, LDS_BYTES, stream>>>(fb, S, P);
    k_final<<<1, 1024, 0, stream>>>(S, P, (float*)d_out);
}